// Round 1
// 1791.982 us; speedup vs baseline: 1.1103x; 1.1103x over previous
//
#include <hip/hip_runtime.h>
#include <math.h>

#define NEGINF_F (-1e38f)

typedef _Float16 half8 __attribute__((ext_vector_type(8)));
typedef float floatx4 __attribute__((ext_vector_type(4)));

__device__ __forceinline__ void async_lds16(const void* g, void* l) {
    __builtin_amdgcn_global_load_lds(
        (const __attribute__((address_space(1))) void*)g,
        (__attribute__((address_space(3))) void*)l, 16, 0, 0);
}

// ---------------------------------------------------------------------------
// tscores[k][j] = sum_a A_from[k][a]*A_to[a][j]  (+ NEGINF on diagonal)
// ---------------------------------------------------------------------------
__global__ __launch_bounds__(128) void tsc_kernel(
    const float* __restrict__ Af, const float* __restrict__ At,
    float* __restrict__ tsc)
{
    int k = blockIdx.x, j = threadIdx.x;
    float s = 0.f;
#pragma unroll 8
    for (int a = 0; a < 64; ++a) s = fmaf(Af[k * 64 + a], At[a * 128 + j], s);
    if (j == k) s += NEGINF_F;
    tsc[k * 128 + j] = s;
}

// ---------------------------------------------------------------------------
// pi = log_softmax(uniqenc @ W_init + b_init) ; one block per batch row
// ---------------------------------------------------------------------------
__global__ __launch_bounds__(128) void pi_kernel(
    const float* __restrict__ u, const float* __restrict__ W,
    const float* __restrict__ b, float* __restrict__ pi)
{
    __shared__ float ul[1024];
    __shared__ float red[2];
    int bi = blockIdx.x, j = threadIdx.x;
    for (int i = j; i < 1024; i += 128) ul[i] = u[bi * 1024 + i];
    __syncthreads();
    float acc = b[j];
#pragma unroll 4
    for (int i = 0; i < 1024; ++i) acc = fmaf(ul[i], W[i * 128 + j], acc);
    float m = acc;
#pragma unroll
    for (int off = 32; off >= 1; off >>= 1) m = fmaxf(m, __shfl_xor(m, off, 64));
    if ((j & 63) == 0) red[j >> 6] = m;
    __syncthreads();
    m = fmaxf(red[0], red[1]);
    float s = expf(acc - m);
#pragma unroll
    for (int off = 32; off >= 1; off >>= 1) s += __shfl_xor(s, off, 64);
    __syncthreads();
    if ((j & 63) == 0) red[j >> 6] = s;
    __syncthreads();
    float logZ = m + logf(red[0] + red[1]);
    pi[bi * 128 + j] = acc - logZ;
}

// ---------------------------------------------------------------------------
// fp32 -> fp16 elementwise (uniqenc)
// ---------------------------------------------------------------------------
__global__ __launch_bounds__(256) void cvt_kernel(
    const float* __restrict__ in, _Float16* __restrict__ out)
{
    int i = (blockIdx.x * 256 + threadIdx.x) * 4;
    float4 v = *(const float4*)&in[i];
    _Float16 h[4] = {(_Float16)v.x, (_Float16)v.y, (_Float16)v.z, (_Float16)v.w};
    *(ushort4*)&out[i] = *(ushort4*)h;
}

// ---------------------------------------------------------------------------
// MFMA fp16 GEMM: C = A(MxK fp16) @ B(KxN fp32, converted in staging) + bias
// 256x128 tile, BK=32, 512 threads (8 waves, 64x64 quadrant each, 4x4 MFMA).
// Grid is 1D-flattened (4 row-blocks x N/128 col-blocks), XCD-chunked so the
// 4 row-blocks sharing a B column-panel run consecutively on one XCD and the
// whole grid is co-resident (2 blocks/CU) -> each 32xN K-slab of B is fetched
// from HBM ~once and shared through L2/L3 instead of re-fetched ~4x.
// A staged via global_load_lds(16B); B transposed+cvt'd through VGPRs.
// XOR swizzle (seg p = q ^ ((row>>1)&3)) keeps ds_read_b128 at 2-way.
// SPLIT_RELU=1: out = fp16 relu(acc+bias)  (GEMM2 -> h)
// SPLIT_RELU=0: out = fp32 acc+bias        (GEMM3 -> cond)
// ---------------------------------------------------------------------------
template <int SPLIT_RELU>
__global__ __launch_bounds__(512, 4) void gemm_f16(
    const _Float16* __restrict__ A, const float* __restrict__ B,
    const float* __restrict__ bias, float* __restrict__ Cf,
    _Float16* __restrict__ Ch, int Kd, int N)
{
    __shared__ _Float16 Asm[256 * 32];
    __shared__ _Float16 Bsm[128 * 32];
    const int tid = threadIdx.x;

    // XCD-chunked decomposition: f%8 = XCD (dispatch round-robin),
    // within an XCD: row-block fastest, then column.
    const int f = blockIdx.x;
    const int xcd = f & 7;
    const int idx = f >> 3;
    const int cols_per_xcd = gridDim.x >> 5;  // (grid/8 XCDs)/4 row-blocks
    const int col = xcd * cols_per_xcd + (idx >> 2);
    const int rowb = idx & 3;
    const int row0 = rowb * 256, col0 = col * 128;

    // A staging: 2 chunks of 16B per thread, LDS offset = u*16B (lane-ordered)
    const int u0 = tid, u1 = tid + 512;
    const int ar0 = u0 >> 2, ap0 = u0 & 3;
    const int ar1 = u1 >> 2, ap1 = u1 & 3;
    const int aq0 = ap0 ^ ((ar0 >> 1) & 3);
    const int aq1 = ap1 ^ ((ar1 >> 1) & 3);
    const _Float16* Arow0 = A + (size_t)(row0 + ar0) * Kd + aq0 * 8;
    const _Float16* Arow1 = A + (size_t)(row0 + ar1) * Kd + aq1 * 8;

    // B loads: thread covers row k=tid>>4, 2 float4 chunks along n
    const int bk = tid >> 4;
    const int bn = (tid & 15) * 4;
    const float* Bptr = B + (size_t)bk * N + col0 + bn;
    const int bp_base = bk >> 3, be = bk & 7;

    const int lane = tid & 63;
    const int wid = tid >> 6;
    const int wm = (wid & 3) * 64, wn = (wid >> 2) * 64;
    const int lr = lane & 15, lq = lane >> 4;

    floatx4 acc[4][4];
#pragma unroll
    for (int i = 0; i < 4; ++i)
#pragma unroll
        for (int j = 0; j < 4; ++j) acc[i][j] = (floatx4)0.f;

    const int nsteps = Kd / 32;
    float4 breg[2];
#pragma unroll
    for (int c = 0; c < 2; ++c) breg[c] = *(const float4*)(Bptr + c * 64);

    for (int s = 0; s < nsteps; ++s) {
        const int k0 = s * 32;
        __syncthreads();  // LDS consumers of step s-1 done
        async_lds16(Arow0 + k0, &Asm[u0 * 8]);
        async_lds16(Arow1 + k0, &Asm[u1 * 8]);
        // B: cvt fp32->fp16, write transposed+swizzled
#pragma unroll
        for (int c = 0; c < 2; ++c) {
            float vv[4] = {breg[c].x, breg[c].y, breg[c].z, breg[c].w};
#pragma unroll
            for (int i = 0; i < 4; ++i) {
                int n = bn + c * 64 + i;
                int p = bp_base ^ ((n >> 1) & 3);
                Bsm[n * 32 + p * 8 + be] = (_Float16)vv[i];
            }
        }
        __syncthreads();  // drains A async + B lds writes
        if (s + 1 < nsteps) {
#pragma unroll
            for (int c = 0; c < 2; ++c)
                breg[c] = *(const float4*)(Bptr + (size_t)(k0 + 32) * N + c * 64);
        }
        half8 af[4], bf[4];
#pragma unroll
        for (int i = 0; i < 4; ++i) {
            int r = wm + i * 16 + lr;
            int p = lq ^ ((r >> 1) & 3);
            af[i] = *(half8*)&Asm[r * 32 + p * 8];
        }
#pragma unroll
        for (int j = 0; j < 4; ++j) {
            int r = wn + j * 16 + lr;
            int p = lq ^ ((r >> 1) & 3);
            bf[j] = *(half8*)&Bsm[r * 32 + p * 8];
        }
#pragma unroll
        for (int i = 0; i < 4; ++i)
#pragma unroll
            for (int j = 0; j < 4; ++j)
                acc[i][j] = __builtin_amdgcn_mfma_f32_16x16x32_f16(
                    af[i], bf[j], acc[i][j], 0, 0, 0);
    }

    // epilogue: C/D layout col=lane&15, row=(lane>>4)*4+reg
#pragma unroll
    for (int i = 0; i < 4; ++i) {
#pragma unroll
        for (int j = 0; j < 4; ++j) {
            int col_ = col0 + wn + j * 16 + lr;
            float bv = bias[col_];
#pragma unroll
            for (int rr = 0; rr < 4; ++rr) {
                int row = row0 + wm + i * 16 + lq * 4 + rr;
                float v = acc[i][j][rr] + bv;
                if (SPLIT_RELU) {
                    v = fmaxf(v, 0.f);
                    Ch[(size_t)row * N + col_] = (_Float16)v;
                } else {
                    Cf[(size_t)row * N + col_] = v;
                }
            }
        }
    }
}

// ---------------------------------------------------------------------------
// trans: per batch b, S[k][j] = tsc[k][j] + dot64(cond_from[b,k], cond_to[b,j]);
// P[b,k,j] = softmax_j(S)[k][j]
// ---------------------------------------------------------------------------
__global__ __launch_bounds__(256) void trans_kernel(
    const float* __restrict__ cond, const float* __restrict__ tsc,
    float* __restrict__ P)
{
    __shared__ float cf[128 * 68];
    __shared__ float ct[128 * 68];
    int b = blockIdx.x, tid = threadIdx.x;
    const float* cb = cond + b * 16384;
    for (int u = tid; u < 2048; u += 256) {
        int k = u >> 4, a4 = (u & 15) * 4;
        *(float4*)&cf[k * 68 + a4] = *(const float4*)&cb[k * 128 + a4];
        *(float4*)&ct[k * 68 + a4] = *(const float4*)&cb[k * 128 + 64 + a4];
    }
    __syncthreads();
    int w = tid >> 6, lane = tid & 63;
    for (int k = w; k < 128; k += 4) {
        float s0 = tsc[k * 128 + lane];
        float s1 = tsc[k * 128 + 64 + lane];
#pragma unroll
        for (int a4 = 0; a4 < 64; a4 += 4) {
            float4 c4 = *(float4*)&cf[k * 68 + a4];
            float4 t0 = *(float4*)&ct[lane * 68 + a4];
            float4 t1 = *(float4*)&ct[(lane + 64) * 68 + a4];
            s0 = fmaf(c4.x, t0.x, fmaf(c4.y, t0.y, fmaf(c4.z, t0.z, fmaf(c4.w, t0.w, s0))));
            s1 = fmaf(c4.x, t1.x, fmaf(c4.y, t1.y, fmaf(c4.z, t1.z, fmaf(c4.w, t1.w, s1))));
        }
        float m = fmaxf(s0, s1);
#pragma unroll
        for (int off = 32; off >= 1; off >>= 1) m = fmaxf(m, __shfl_xor(m, off, 64));
        float es = expf(s0 - m) + expf(s1 - m);
#pragma unroll
        for (int off = 32; off >= 1; off >>= 1) es += __shfl_xor(es, off, 64);
        float logZ = m + logf(es);
        P[(b * 128 + k) * 128 + lane] = expf(s0 - logZ);
        P[(b * 128 + k) * 128 + 64 + lane] = expf(s1 - logZ);
    }
}

// ---------------------------------------------------------------------------
// scan: one block per batch. P[b] staged in LDS.
// ---------------------------------------------------------------------------
__global__ __launch_bounds__(256) void scan_kernel(
    const float* __restrict__ obs, const float* __restrict__ pi,
    const float* __restrict__ P, float* __restrict__ out)
{
    __shared__ float Pl[128 * 128];
    __shared__ float part[2][128];
    __shared__ float e_lds[128];
    __shared__ float redm[2];
    __shared__ float reds[2];
    const float LENLP = -1.791759469228055f;  // -log(6)
    int b = blockIdx.x, tid = threadIdx.x;
    for (int u = tid; u < 4096; u += 256)
        *(float4*)&Pl[u * 4] = *(const float4*)&P[b * 16384 + u * 4];

    float bufr[6];
    if (tid < 128) {
        bufr[0] = pi[b * 128 + tid];
#pragma unroll
        for (int l = 1; l < 6; ++l) bufr[l] = NEGINF_F;
    }
    __syncthreads();

    const int j = tid & 127, half = tid >> 7, k0 = half * 64;

    for (int t = 0; t < 60; ++t) {
        float alpha = NEGINF_F, ev = 0.f;
        if (tid < 128) {
            float vals[6];
            float am = -3.0e38f;
#pragma unroll
            for (int l = 0; l < 6; ++l) {
                int tt = t - l;
                float v = -3.0e38f;
                if (tt >= 0)
                    v = bufr[l] + obs[((l * 60 + tt) * 1024 + b) * 128 + tid] + LENLP;
                vals[l] = v;
                am = fmaxf(am, v);
            }
            float ss = 0.f;
#pragma unroll
            for (int l = 0; l < 6; ++l) ss += expf(vals[l] - am);
            alpha = am + logf(ss);
            float mm = alpha;
#pragma unroll
            for (int off = 32; off >= 1; off >>= 1) mm = fmaxf(mm, __shfl_xor(mm, off, 64));
            if ((tid & 63) == 0) redm[tid >> 6] = mm;
        }
        __syncthreads();
        float m = fmaxf(redm[0], redm[1]);
        if (tid < 128) {
            ev = expf(alpha - m);
            e_lds[tid] = ev;
        }
        __syncthreads();
        float acc = 0.f;
#pragma unroll 8
        for (int kk = 0; kk < 64; ++kk)
            acc = fmaf(e_lds[k0 + kk], Pl[(k0 + kk) * 128 + j], acc);
        part[half][j] = acc;
        __syncthreads();
        if (tid < 128) {
            float s = part[0][tid] + part[1][tid];
            float astar = m + logf(s);
#pragma unroll
            for (int l = 5; l >= 1; --l) bufr[l] = bufr[l - 1];
            bufr[0] = astar;
        }
        if (t == 59) {
            float sv = (tid < 128) ? ev : 0.f;
#pragma unroll
            for (int off = 32; off >= 1; off >>= 1) sv += __shfl_xor(sv, off, 64);
            if (tid < 128 && (tid & 63) == 0) reds[tid >> 6] = sv;
            __syncthreads();
            if (tid == 0) out[b] = m + logf(reds[0] + reds[1]);
        }
    }
}

// ---------------------------------------------------------------------------
extern "C" void kernel_launch(void* const* d_in, const int* in_sizes, int n_in,
                              void* d_out, int out_size, void* d_ws, size_t ws_size,
                              hipStream_t stream)
{
    const float* uniqenc = (const float*)d_in[0];
    const float* obs_lps = (const float*)d_in[1];
    const float* W_init  = (const float*)d_in[2];
    const float* b_init  = (const float*)d_in[3];
    const float* A_from  = (const float*)d_in[4];
    const float* A_to    = (const float*)d_in[5];
    const float* W_c1    = (const float*)d_in[6];
    const float* b_c1    = (const float*)d_in[7];
    const float* W_c2    = (const float*)d_in[8];
    const float* b_c2    = (const float*)d_in[9];
    float* out = (float*)d_out;

    float* ws   = (float*)d_ws;
    float* pi   = ws;                    // 1024*128
    float* cond = pi + 131072;           // 1024*16384
    float* tsc  = cond + 16777216;       // 128*128
    float* P    = tsc + 16384;           // 1024*128*128
    _Float16* u16 = (_Float16*)(P + 16777216);   // 1024*1024 fp16
    _Float16* h16 = u16 + 1048576;               // 1024*8192 fp16

    tsc_kernel<<<128, 128, 0, stream>>>(A_from, A_to, tsc);
    cvt_kernel<<<1024, 256, 0, stream>>>(uniqenc, u16);
    pi_kernel<<<1024, 128, 0, stream>>>(uniqenc, W_init, b_init, pi);
    // GEMM2: h = relu(u @ W_c1 + b_c1)   (1024 x 1024 x 8192), fp16 out
    // grid = 4 row-blocks x 64 col-blocks = 256, XCD-chunked 1D
    gemm_f16<1><<<dim3(256), 512, 0, stream>>>(u16, W_c1, b_c1,
                                               nullptr, h16, 1024, 8192);
    // GEMM3: cond = h @ W_c2 + b_c2      (1024 x 8192 x 16384), fp32 out
    // grid = 4 row-blocks x 128 col-blocks = 512, XCD-chunked 1D
    gemm_f16<0><<<dim3(512), 512, 0, stream>>>(h16, W_c2, b_c2,
                                               cond, nullptr, 8192, 16384);
    trans_kernel<<<1024, 256, 0, stream>>>(cond, tsc, P);
    scan_kernel<<<1024, 256, 0, stream>>>(obs_lps, pi, P, out);
}

// Round 2
// 1431.828 us; speedup vs baseline: 1.3896x; 1.2515x over previous
//
#include <hip/hip_runtime.h>
#include <math.h>

#define NEGINF_F (-1e38f)

typedef _Float16 half8 __attribute__((ext_vector_type(8)));
typedef _Float16 half4 __attribute__((ext_vector_type(4)));
typedef float floatx4 __attribute__((ext_vector_type(4)));

__device__ __forceinline__ void async_lds16(const void* g, void* l) {
    __builtin_amdgcn_global_load_lds(
        (const __attribute__((address_space(1))) void*)g,
        (__attribute__((address_space(3))) void*)l, 16, 0, 0);
}

// ---------------------------------------------------------------------------
// tscores[k][j] = sum_a A_from[k][a]*A_to[a][j]  (+ NEGINF on diagonal)
// ---------------------------------------------------------------------------
__global__ __launch_bounds__(128) void tsc_kernel(
    const float* __restrict__ Af, const float* __restrict__ At,
    float* __restrict__ tsc)
{
    int k = blockIdx.x, j = threadIdx.x;
    float s = 0.f;
#pragma unroll 8
    for (int a = 0; a < 64; ++a) s = fmaf(Af[k * 64 + a], At[a * 128 + j], s);
    if (j == k) s += NEGINF_F;
    tsc[k * 128 + j] = s;
}

// ---------------------------------------------------------------------------
// pi = log_softmax(uniqenc @ W_init + b_init) ; one block per batch row
// ---------------------------------------------------------------------------
__global__ __launch_bounds__(128) void pi_kernel(
    const float* __restrict__ u, const float* __restrict__ W,
    const float* __restrict__ b, float* __restrict__ pi)
{
    __shared__ float ul[1024];
    __shared__ float red[2];
    int bi = blockIdx.x, j = threadIdx.x;
    for (int i = j; i < 1024; i += 128) ul[i] = u[bi * 1024 + i];
    __syncthreads();
    float acc = b[j];
#pragma unroll 4
    for (int i = 0; i < 1024; ++i) acc = fmaf(ul[i], W[i * 128 + j], acc);
    float m = acc;
#pragma unroll
    for (int off = 32; off >= 1; off >>= 1) m = fmaxf(m, __shfl_xor(m, off, 64));
    if ((j & 63) == 0) red[j >> 6] = m;
    __syncthreads();
    m = fmaxf(red[0], red[1]);
    float s = expf(acc - m);
#pragma unroll
    for (int off = 32; off >= 1; off >>= 1) s += __shfl_xor(s, off, 64);
    __syncthreads();
    if ((j & 63) == 0) red[j >> 6] = s;
    __syncthreads();
    float logZ = m + logf(red[0] + red[1]);
    pi[bi * 128 + j] = acc - logZ;
}

// ---------------------------------------------------------------------------
// fp32 -> fp16 elementwise (uniqenc)
// ---------------------------------------------------------------------------
__global__ __launch_bounds__(256) void cvt_kernel(
    const float* __restrict__ in, _Float16* __restrict__ out)
{
    int i = (blockIdx.x * 256 + threadIdx.x) * 4;
    float4 v = *(const float4*)&in[i];
    _Float16 h[4] = {(_Float16)v.x, (_Float16)v.y, (_Float16)v.z, (_Float16)v.w};
    *(ushort4*)&out[i] = *(ushort4*)h;
}

// ---------------------------------------------------------------------------
// MFMA fp16 GEMM: C = A(MxK fp16) @ B(KxN fp32, converted in staging) + bias
// 256x128 tile, BK=32, 512 threads (8 waves, 64x64 quadrant each, 4x4 MFMA).
// XCD-chunked 1D grid (see round 1), all blocks co-resident (2/CU).
// Staging split: waves 0-3 issue all A global_load_lds (4x16B each, lane-
// ordered, source pre-swizzled). Waves 4-7 stage B: each thread loads 4
// float4 from 4 consecutive K rows (coalesced 512B/instr), transposes 4x4
// in registers, cvt fp32->fp16, and writes 4x ds_write_b64 into the
// XOR-swizzled [n][k] layout -- replaces the old 16-way-conflicted scalar
// stores (was 36% of GEMM cycles per SQ_LDS_BANK_CONFLICT).
// ---------------------------------------------------------------------------
template <int SPLIT_RELU>
__global__ __launch_bounds__(512, 4) void gemm_f16(
    const _Float16* __restrict__ A, const float* __restrict__ B,
    const float* __restrict__ bias, float* __restrict__ Cf,
    _Float16* __restrict__ Ch, int Kd, int N)
{
    __shared__ _Float16 Asm[256 * 32];
    __shared__ _Float16 Bsm[128 * 32];
    const int tid = threadIdx.x;

    const int f = blockIdx.x;
    const int xcd = f & 7;
    const int idx = f >> 3;
    const int cols_per_xcd = gridDim.x >> 5;
    const int col = xcd * cols_per_xcd + (idx >> 2);
    const int rowb = idx & 3;
    const int row0 = rowb * 256, col0 = col * 128;

    // ---- A staging setup (threads 0..255): 4 chunks of 16B each ----
    const _Float16* Abase[4];
    if (tid < 256) {
#pragma unroll
        for (int c = 0; c < 4; ++c) {
            int u = c * 256 + tid;
            int ar = u >> 2, ap = u & 3;
            int aq = ap ^ ((ar >> 1) & 3);   // source pre-swizzle
            Abase[c] = A + (size_t)(row0 + ar) * Kd + aq * 8;
        }
    }

    // ---- B staging setup (threads 256..511): 4 rows x 4 cols ----
    const int t = tid - 256;                 // 0..255 (only valid tid>=256)
    const int bn0 = (t & 31) * 4;            // n within tile
    const int bk0 = (t >> 5) * 4;            // k within tile (0,4,..,28)
    const float* Bbase = B + (size_t)bk0 * N + col0 + bn0;

    const int lane = tid & 63;
    const int wid = tid >> 6;
    const int wm = (wid & 3) * 64, wn = (wid >> 2) * 64;
    const int lr = lane & 15, lq = lane >> 4;

    floatx4 acc[4][4];
#pragma unroll
    for (int i = 0; i < 4; ++i)
#pragma unroll
        for (int j = 0; j < 4; ++j) acc[i][j] = (floatx4)0.f;

    const int nsteps = Kd / 32;
    float4 breg[4];
    if (tid >= 256) {
#pragma unroll
        for (int r = 0; r < 4; ++r)
            breg[r] = *(const float4*)(Bbase + (size_t)r * N);
    }

    for (int s = 0; s < nsteps; ++s) {
        const int k0 = s * 32;
        __syncthreads();  // LDS consumers of step s-1 done
        if (tid < 256) {
#pragma unroll
            for (int c = 0; c < 4; ++c)
                async_lds16(Abase[c] + k0, &Asm[(c * 256 + tid) * 8]);
        } else {
            // in-register 4x4 transpose + cvt, write 4 fp16 along k per n
#pragma unroll
            for (int i = 0; i < 4; ++i) {
                int n = bn0 + i;
                int p = (bk0 >> 3) ^ ((n >> 1) & 3);
                half4 h;
#pragma unroll
                for (int r = 0; r < 4; ++r)
                    h[r] = (_Float16)(((const float*)&breg[r])[i]);
                *(half4*)&Bsm[n * 32 + p * 8 + (bk0 & 4)] = h;
            }
        }
        __syncthreads();  // drains A async + B lds writes
        if (s + 1 < nsteps && tid >= 256) {
#pragma unroll
            for (int r = 0; r < 4; ++r)
                breg[r] = *(const float4*)(Bbase + (size_t)(k0 + 32 + r) * N);
        }
        half8 af[4], bf[4];
#pragma unroll
        for (int i = 0; i < 4; ++i) {
            int r = wm + i * 16 + lr;
            int p = lq ^ ((r >> 1) & 3);
            af[i] = *(half8*)&Asm[r * 32 + p * 8];
        }
#pragma unroll
        for (int j = 0; j < 4; ++j) {
            int r = wn + j * 16 + lr;
            int p = lq ^ ((r >> 1) & 3);
            bf[j] = *(half8*)&Bsm[r * 32 + p * 8];
        }
#pragma unroll
        for (int i = 0; i < 4; ++i)
#pragma unroll
            for (int j = 0; j < 4; ++j)
                acc[i][j] = __builtin_amdgcn_mfma_f32_16x16x32_f16(
                    af[i], bf[j], acc[i][j], 0, 0, 0);
    }

    // epilogue: C/D layout col=lane&15, row=(lane>>4)*4+reg
#pragma unroll
    for (int i = 0; i < 4; ++i) {
#pragma unroll
        for (int j = 0; j < 4; ++j) {
            int col_ = col0 + wn + j * 16 + lr;
            float bv = bias[col_];
#pragma unroll
            for (int rr = 0; rr < 4; ++rr) {
                int row = row0 + wm + i * 16 + lq * 4 + rr;
                float v = acc[i][j][rr] + bv;
                if (SPLIT_RELU) {
                    v = fmaxf(v, 0.f);
                    Ch[(size_t)row * N + col_] = (_Float16)v;
                } else {
                    Cf[(size_t)row * N + col_] = v;
                }
            }
        }
    }
}

// ---------------------------------------------------------------------------
// trans: per batch b, S[k][j] = tsc[k][j] + dot64(cond_from[b,k], cond_to[b,j]);
// P[b,k,j] = softmax_j(S)[k][j].
// Register-tiled: each wave processes 4 k-rows at a time, so the per-lane
// ct reads (the LDS-bound term) are amortized 4x (256 vs 1024 b128/wave).
// ---------------------------------------------------------------------------
__global__ __launch_bounds__(256) void trans_kernel(
    const float* __restrict__ cond, const float* __restrict__ tsc,
    float* __restrict__ P)
{
    __shared__ float cf[128 * 68];
    __shared__ float ct[128 * 68];
    int b = blockIdx.x, tid = threadIdx.x;
    const float* cb = cond + b * 16384;
    for (int u = tid; u < 2048; u += 256) {
        int k = u >> 4, a4 = (u & 15) * 4;
        *(float4*)&cf[k * 68 + a4] = *(const float4*)&cb[k * 128 + a4];
        *(float4*)&ct[k * 68 + a4] = *(const float4*)&cb[k * 128 + 64 + a4];
    }
    __syncthreads();
    int w = tid >> 6, lane = tid & 63;
    for (int i = 0; i < 8; ++i) {
        int kb = w * 4 + i * 16;
        float s[4][2];
#pragma unroll
        for (int r = 0; r < 4; ++r) {
            s[r][0] = tsc[(kb + r) * 128 + lane];
            s[r][1] = tsc[(kb + r) * 128 + 64 + lane];
        }
#pragma unroll 4
        for (int a4 = 0; a4 < 64; a4 += 4) {
            float4 t0 = *(float4*)&ct[lane * 68 + a4];
            float4 t1 = *(float4*)&ct[(lane + 64) * 68 + a4];
#pragma unroll
            for (int r = 0; r < 4; ++r) {
                float4 c4 = *(float4*)&cf[(kb + r) * 68 + a4];
                s[r][0] = fmaf(c4.x, t0.x, fmaf(c4.y, t0.y,
                          fmaf(c4.z, t0.z, fmaf(c4.w, t0.w, s[r][0]))));
                s[r][1] = fmaf(c4.x, t1.x, fmaf(c4.y, t1.y,
                          fmaf(c4.z, t1.z, fmaf(c4.w, t1.w, s[r][1]))));
            }
        }
#pragma unroll
        for (int r = 0; r < 4; ++r) {
            float m = fmaxf(s[r][0], s[r][1]);
#pragma unroll
            for (int off = 32; off >= 1; off >>= 1)
                m = fmaxf(m, __shfl_xor(m, off, 64));
            float es = expf(s[r][0] - m) + expf(s[r][1] - m);
#pragma unroll
            for (int off = 32; off >= 1; off >>= 1)
                es += __shfl_xor(es, off, 64);
            float logZ = m + logf(es);
            P[((size_t)b * 128 + kb + r) * 128 + lane] = expf(s[r][0] - logZ);
            P[((size_t)b * 128 + kb + r) * 128 + 64 + lane] = expf(s[r][1] - logZ);
        }
    }
}

// ---------------------------------------------------------------------------
// scan: one block per batch. P[b] staged TRANSPOSED in LDS (PlT[j][k]) with
// chunk-XOR swizzle so the per-step matvec is 16 ds_read_b128 per lane
// (conflict-free at floor) instead of 64 ds_read_b32. obs loads are
// double-buffered one step ahead so HBM latency hides under the matvec.
// ---------------------------------------------------------------------------
__global__ __launch_bounds__(256) void scan_kernel(
    const float* __restrict__ obs, const float* __restrict__ pi,
    const float* __restrict__ P, float* __restrict__ out)
{
    __shared__ float PlT[128 * 128];  // PlT[j][k] = P[k][j], chunk-swizzled
    __shared__ float part[2][128];
    __shared__ __align__(16) float e_lds[128];
    __shared__ float redm[2];
    __shared__ float reds[2];
    const float LENLP = -1.791759469228055f;  // -log(6)
    int b = blockIdx.x, tid = threadIdx.x;

    // stage P transposed: read coalesced float4 rows, scatter scalar writes.
    // swizzle: elem(j,k) = j*128 + ((k>>2 ^ (j&7))<<2) + (k&3)
    for (int u = tid; u < 4096; u += 256) {
        float4 v = *(const float4*)&P[(size_t)b * 16384 + u * 4];
        int k = u >> 5, n0 = (u & 31) * 4;
#pragma unroll
        for (int i = 0; i < 4; ++i) {
            int n = n0 + i;
            PlT[n * 128 + ((((k) >> 2) ^ (n & 7)) << 2) + (k & 3)] =
                ((const float*)&v)[i];
        }
    }

    float bufr[6];
    float onext[6];
    if (tid < 128) {
        bufr[0] = pi[b * 128 + tid];
#pragma unroll
        for (int l = 1; l < 6; ++l) bufr[l] = NEGINF_F;
        // prefetch obs for t=0 (only l=0 valid)
        onext[0] = obs[(size_t)(0 * 1024 + b) * 128 + tid];
#pragma unroll
        for (int l = 1; l < 6; ++l) onext[l] = 0.f;
    }
    __syncthreads();

    const int j = tid & 127, half = tid >> 7, c0 = half * 16;

    for (int t = 0; t < 60; ++t) {
        float alpha = NEGINF_F, ev = 0.f;
        float ocur[6];
        if (tid < 128) {
#pragma unroll
            for (int l = 0; l < 6; ++l) ocur[l] = onext[l];
            // prefetch t+1 (issues early; latency hides under matvec)
            if (t + 1 < 60) {
#pragma unroll
                for (int l = 0; l < 6; ++l) {
                    int tt = t + 1 - l;
                    if (tt >= 0)
                        onext[l] = obs[((size_t)(l * 60 + tt) * 1024 + b) * 128 + tid];
                }
            }
            float vals[6];
            float am = -3.0e38f;
#pragma unroll
            for (int l = 0; l < 6; ++l) {
                int tt = t - l;
                float v = -3.0e38f;
                if (tt >= 0) v = bufr[l] + ocur[l] + LENLP;
                vals[l] = v;
                am = fmaxf(am, v);
            }
            float ss = 0.f;
#pragma unroll
            for (int l = 0; l < 6; ++l) ss += expf(vals[l] - am);
            alpha = am + logf(ss);
            float mm = alpha;
#pragma unroll
            for (int off = 32; off >= 1; off >>= 1)
                mm = fmaxf(mm, __shfl_xor(mm, off, 64));
            if ((tid & 63) == 0) redm[tid >> 6] = mm;
        }
        __syncthreads();
        float m = fmaxf(redm[0], redm[1]);
        if (tid < 128) {
            ev = expf(alpha - m);
            e_lds[tid] = ev;
        }
        __syncthreads();
        // matvec: acc_j = sum_k e[k] * P[k][j] over this half's 64 k
        float acc = 0.f;
#pragma unroll 4
        for (int cc = 0; cc < 16; ++cc) {
            int c = c0 + cc;                       // global k-chunk
            float4 p4 = *(float4*)&PlT[j * 128 + ((c ^ (j & 7)) << 2)];
            float4 e4 = *(float4*)&e_lds[c * 4];
            acc = fmaf(e4.x, p4.x, fmaf(e4.y, p4.y,
                  fmaf(e4.z, p4.z, fmaf(e4.w, p4.w, acc))));
        }
        part[half][j] = acc;
        __syncthreads();
        if (tid < 128) {
            float s = part[0][tid] + part[1][tid];
            float astar = m + logf(s);
#pragma unroll
            for (int l = 5; l >= 1; --l) bufr[l] = bufr[l - 1];
            bufr[0] = astar;
        }
        if (t == 59) {
            float sv = (tid < 128) ? ev : 0.f;
#pragma unroll
            for (int off = 32; off >= 1; off >>= 1) sv += __shfl_xor(sv, off, 64);
            if (tid < 128 && (tid & 63) == 0) reds[tid >> 6] = sv;
            __syncthreads();
            if (tid == 0) out[b] = m + logf(reds[0] + reds[1]);
        }
    }
}

// ---------------------------------------------------------------------------
extern "C" void kernel_launch(void* const* d_in, const int* in_sizes, int n_in,
                              void* d_out, int out_size, void* d_ws, size_t ws_size,
                              hipStream_t stream)
{
    const float* uniqenc = (const float*)d_in[0];
    const float* obs_lps = (const float*)d_in[1];
    const float* W_init  = (const float*)d_in[2];
    const float* b_init  = (const float*)d_in[3];
    const float* A_from  = (const float*)d_in[4];
    const float* A_to    = (const float*)d_in[5];
    const float* W_c1    = (const float*)d_in[6];
    const float* b_c1    = (const float*)d_in[7];
    const float* W_c2    = (const float*)d_in[8];
    const float* b_c2    = (const float*)d_in[9];
    float* out = (float*)d_out;

    float* ws   = (float*)d_ws;
    float* pi   = ws;                    // 1024*128
    float* cond = pi + 131072;           // 1024*16384
    float* tsc  = cond + 16777216;       // 128*128
    float* P    = tsc + 16384;           // 1024*128*128
    _Float16* u16 = (_Float16*)(P + 16777216);   // 1024*1024 fp16
    _Float16* h16 = u16 + 1048576;               // 1024*8192 fp16

    tsc_kernel<<<128, 128, 0, stream>>>(A_from, A_to, tsc);
    cvt_kernel<<<1024, 256, 0, stream>>>(uniqenc, u16);
    pi_kernel<<<1024, 128, 0, stream>>>(uniqenc, W_init, b_init, pi);
    // GEMM2: h = relu(u @ W_c1 + b_c1)   (1024 x 1024 x 8192), fp16 out
    gemm_f16<1><<<dim3(256), 512, 0, stream>>>(u16, W_c1, b_c1,
                                               nullptr, h16, 1024, 8192);
    // GEMM3: cond = h @ W_c2 + b_c2      (1024 x 8192 x 16384), fp32 out
    gemm_f16<0><<<dim3(512), 512, 0, stream>>>(h16, W_c2, b_c2,
                                               cond, nullptr, 8192, 16384);
    trans_kernel<<<1024, 256, 0, stream>>>(cond, tsc, P);
    scan_kernel<<<1024, 256, 0, stream>>>(obs_lps, pi, P, out);
}